// Round 4
// baseline (142.227 us; speedup 1.0000x reference)
//
#include <hip/hip_runtime.h>

// ForwardKinematics fp32: rotations (B,24,4) wxyz + positions (B,24,3)
// -> global joint positions (B,24,3). Fixed SMPL tree.
//
// Round 10: persistent software-pipelined blocks (T14 async-STAGE).
//  - grid = 768 (3 blocks/CU, all resident). Each block strides over
//    ~3.6 chunks of SPB=48. Next chunk's global loads are issued right
//    after the LDS scatter, so they fly during compute+store (~2us >>
//    ~900cy HBM latency): HBM never idles during compute phases.
//  - Separate ldsO output region: pos never overwritten -> no pb-gather
//    (saves 33 VGPRs + one barrier per iter).
//  - RPITCH 100 (16B-aligned): quat reads are single ds_read_b128,
//    bank-uniform (8 lanes per 4-bank group = b128 minimum cycles).
//  - (256,3) launch bounds: 170-VGPR cap, no spill (r8 lesson).
//  - LDS 47.25 KB -> 3 blocks/CU. 4-way wave-uniform DAG split (r7).

typedef float f32x4 __attribute__((ext_vector_type(4)));

struct M { float r0,r1,r2,r3,r4,r5,r6,r7,r8,tx,ty,tz; };

__device__ __forceinline__ M loc(float a, float b, float c, float d,
                                 float px, float py, float pz) {
    float inv = rsqrtf(a*a + b*b + c*c + d*d);
    float qw = a*inv, qx = b*inv, qy = c*inv, qz = d*inv;
    float x2 = qx+qx, y2 = qy+qy, z2 = qz+qz;
    float xx = qx*x2, yy = qy*y2, zz = qz*z2;
    float xy = qx*y2, yz = qy*z2, xz = qx*z2;
    float wx = qw*x2, wy = qw*y2, wz = qw*z2;
    M m;
    m.r0 = 1.f-(yy+zz); m.r1 = xy-wz;       m.r2 = xz+wy;
    m.r3 = xy+wz;       m.r4 = 1.f-(xx+zz); m.r5 = yz-wx;
    m.r6 = xz-wy;       m.r7 = yz+wx;       m.r8 = 1.f-(xx+yy);
    m.tx = px; m.ty = py; m.tz = pz;
    return m;
}

__device__ __forceinline__ M mul(const M& a, const M& b) {
    M c;
    c.r0 = a.r0*b.r0 + a.r1*b.r3 + a.r2*b.r6;
    c.r1 = a.r0*b.r1 + a.r1*b.r4 + a.r2*b.r7;
    c.r2 = a.r0*b.r2 + a.r1*b.r5 + a.r2*b.r8;
    c.r3 = a.r3*b.r0 + a.r4*b.r3 + a.r5*b.r6;
    c.r4 = a.r3*b.r1 + a.r4*b.r4 + a.r5*b.r7;
    c.r5 = a.r3*b.r2 + a.r4*b.r5 + a.r5*b.r8;
    c.r6 = a.r6*b.r0 + a.r7*b.r3 + a.r8*b.r6;
    c.r7 = a.r6*b.r1 + a.r7*b.r4 + a.r8*b.r7;
    c.r8 = a.r6*b.r2 + a.r7*b.r5 + a.r8*b.r8;
    c.tx = a.r0*b.tx + a.r1*b.ty + a.r2*b.tz + a.tx;
    c.ty = a.r3*b.tx + a.r4*b.ty + a.r5*b.tz + a.ty;
    c.tz = a.r6*b.tx + a.r7*b.ty + a.r8*b.tz + a.tz;
    return c;
}

#define SPB    48
#define NTHR   256
#define GRID   768   // 3 blocks/CU x 256 CU, all resident
#define RPITCH 100   // 16B-aligned quat rows -> ds_read_b128
#define PPITCH 73    // odd -> conflict-free b32 access
#define OPITCH 73

// Wave-uniform 4-way tree split (verified round 7). MT = matrices computed
// (topological), PR = parent index into MT (-1 = root), writes = suffix
// from WS. Each of 24 joints written exactly once:
// g0 {0,1,2,4,7,10} g1 {5,8,11,3,6,9} g2 {12,15,13,16,18,20,22}
// g3 {14,17,19,21,23}
constexpr int MT0[6]  = {0,1,2,4,7,10};
constexpr int PR0[6]  = {-1,0,0,1,3,4};
constexpr int MT1[8]  = {0,2,5,8,11,3,6,9};
constexpr int PR1[8]  = {-1,0,1,2,3,0,5,6};
constexpr int MT2[11] = {0,3,6,9,12,15,13,16,18,20,22};
constexpr int PR2[11] = {-1,0,1,2,3,4,3,6,7,8,9};
constexpr int MT3[9]  = {0,3,6,9,14,17,19,21,23};
constexpr int PR3[9]  = {-1,0,1,2,3,4,5,6,7};

template<int NM>
__device__ __forceinline__ void run_chain(const int (&MT)[NM], const int (&PR)[NM],
                                          int WS,
                                          const float* __restrict__ R,
                                          const float* __restrict__ P,
                                          float* __restrict__ O) {
    M G[NM];
    {
        f32x4 q = *(const f32x4*)(R);
        G[0] = loc(q.x, q.y, q.z, q.w, P[0], P[1], P[2]);
    }
    if (WS == 0) { O[0]=G[0].tx; O[1]=G[0].ty; O[2]=G[0].tz; }
#pragma unroll
    for (int k = 1; k < NM; ++k) {
        const int j = MT[k];
        f32x4 q = *(const f32x4*)(R + 4*j);
        M L = loc(q.x, q.y, q.z, q.w, P[3*j], P[3*j+1], P[3*j+2]);
        G[k] = mul(G[PR[k]], L);
        if (k >= WS) { O[3*j]=G[k].tx; O[3*j+1]=G[k].ty; O[3*j+2]=G[k].tz; }
    }
}

__global__ __launch_bounds__(NTHR, 3) void fk_kernel(
    const float* __restrict__ rot,   // B*96 floats (quat wxyz per joint)
    const float* __restrict__ pos,   // B*72 floats
    float*       __restrict__ out,   // B*72 floats
    int B)
{
    __shared__ __align__(16) float ldsR[SPB * RPITCH];  // 19200 B
    __shared__ float ldsP[SPB * PPITCH];                // 14016 B
    __shared__ float ldsO[SPB * OPITCH];                // 14016 B

    const int t = threadIdx.x;
    const int nch = (B + SPB - 1) / SPB;
    const size_t limR = (size_t)B * 96;
    const size_t limP = (size_t)B * 72;

    const int w = t >> 6, l = t & 63;

    f32x4 vr[5], vp[4];

    // ---- issue loads for first chunk ----
    int c = blockIdx.x;
    {
        const size_t baseR = (size_t)c * (SPB*96);
        const size_t baseP = (size_t)c * (SPB*72);
#pragma unroll
        for (int i = 0; i < 5; ++i) {
            const bool g = (i < 4) || (t < 128);
            const size_t gi = baseR + (size_t)(i*1024 + 4*t);
            f32x4 v = {0.f,0.f,0.f,0.f};
            if (g && gi < limR) v = *(const f32x4*)(rot + gi);
            vr[i] = v;
        }
#pragma unroll
        for (int i = 0; i < 4; ++i) {
            const bool g = (i < 3) || (t < 96);
            const size_t gi = baseP + (size_t)(i*1024 + 4*t);
            f32x4 v = {0.f,0.f,0.f,0.f};
            if (g && gi < limP) v = *(const f32x4*)(pos + gi);
            vp[i] = v;
        }
    }

    for (; c < nch; c += GRID) {
        __syncthreads();   // previous iteration's stores have read ldsO;
                           // ldsR/ldsP free to overwrite

        // ---- scatter staged regs to pitched LDS ----
        // (compiler inserts the vmcnt waits right here, after the barrier)
#pragma unroll
        for (int i = 0; i < 5; ++i) {
            if ((i < 4) || (t < 128)) {
                const int f = i*1024 + 4*t;
                const int s = f / 96, r = f - 96*s;
                float* d = ldsR + s*RPITCH + r;
                d[0]=vr[i].x; d[1]=vr[i].y; d[2]=vr[i].z; d[3]=vr[i].w;
            }
        }
#pragma unroll
        for (int i = 0; i < 4; ++i) {
            if ((i < 3) || (t < 96)) {
                const int f = i*1024 + 4*t;
                const int s = f / 72, r = f - 72*s;
                float* d = ldsP + s*PPITCH + r;
                d[0]=vp[i].x; d[1]=vp[i].y; d[2]=vp[i].z; d[3]=vp[i].w;
            }
        }
        __syncthreads();

        // ---- issue next chunk's loads: in flight across compute+store ----
        const int cn = c + GRID;
        if (cn < nch) {
            const size_t baseR = (size_t)cn * (SPB*96);
            const size_t baseP = (size_t)cn * (SPB*72);
#pragma unroll
            for (int i = 0; i < 5; ++i) {
                const bool g = (i < 4) || (t < 128);
                const size_t gi = baseR + (size_t)(i*1024 + 4*t);
                f32x4 v = {0.f,0.f,0.f,0.f};
                if (g && gi < limR) v = *(const f32x4*)(rot + gi);
                vr[i] = v;
            }
#pragma unroll
            for (int i = 0; i < 4; ++i) {
                const bool g = (i < 3) || (t < 96);
                const size_t gi = baseP + (size_t)(i*1024 + 4*t);
                f32x4 v = {0.f,0.f,0.f,0.f};
                if (g && gi < limP) v = *(const f32x4*)(pos + gi);
                vp[i] = v;
            }
        }

        // ---- compute: wave w = subtree group, lane l = sample ----
        const int b = c * SPB + l;
        if ((l < SPB) && (b < B)) {
            const float* R = ldsR + l * RPITCH;
            const float* P = ldsP + l * PPITCH;
            float*       O = ldsO + l * OPITCH;
            switch (w) {
                case 0:  run_chain(MT0, PR0, 0, R, P, O); break;
                case 1:  run_chain(MT1, PR1, 2, R, P, O); break;
                case 2:  run_chain(MT2, PR2, 4, R, P, O); break;
                default: run_chain(MT3, PR3, 4, R, P, O); break;
            }
        }
        __syncthreads();   // all ldsO writes visible

        // ---- dense coalesced dwordx4 store ----
        const size_t baseP = (size_t)c * (SPB*72);
#pragma unroll
        for (int n = 0; n < 4; ++n) {
            if ((n < 3) || (t < 96)) {
                const int F = n*1024 + 4*t;
                const int s = F / 72, r = F - 72*s;
                const size_t gi = baseP + (size_t)F;
                if (gi < limP) {
                    f32x4 v = { ldsO[s*OPITCH+r+0], ldsO[s*OPITCH+r+1],
                                ldsO[s*OPITCH+r+2], ldsO[s*OPITCH+r+3] };
                    *(f32x4*)(out + gi) = v;
                }
            }
        }
    }
}

extern "C" void kernel_launch(void* const* d_in, const int* in_sizes, int n_in,
                              void* d_out, int out_size, void* d_ws, size_t ws_size,
                              hipStream_t stream) {
    const int B = out_size / 72;           // (B,24,3)
    const void* rot = nullptr;
    const void* pos = nullptr;
    for (int i = 0; i < n_in; ++i) {       // resolve by size, not order
        if      (in_sizes[i] == B * 96) rot = d_in[i];
        else if (in_sizes[i] == B * 72) pos = d_in[i];
    }
    if (!rot) rot = d_in[2];
    if (!pos) pos = d_in[1];

    const int nch  = (B + SPB - 1) / SPB;
    const int grid = (nch < GRID) ? nch : GRID;
    fk_kernel<<<grid, NTHR, 0, stream>>>(
        (const float*)rot, (const float*)pos, (float*)d_out, B);
}

// Round 5
// 135.917 us; speedup vs baseline: 1.0464x; 1.0464x over previous
//
#include <hip/hip_runtime.h>

// ForwardKinematics fp32: rotations (B,24,4) wxyz + positions (B,24,3)
// -> global joint positions (B,24,3). Fixed SMPL tree.
//
// Round 11: non-persistent consolidation.
//  - r10 post-mortem: persistent grid phase-locked all blocks (HBM 28%,
//    VALU 23%, alternating not overlapping). Non-persistent 2048-block
//    grid restores HW-staggered phase diversity.
//  - SPB=64, 256 thr: ALL lanes active in compute (r9 idled 25%).
//  - Outputs held in regs (<=21 floats/thread) through compute, then
//    scattered into the DEAD quat region of ldsR re-viewed at pitch 73
//    (odd -> conflict-free b32). No separate ldsO. LDS 44.3 KB ->
//    3 blocks/CU.
//  - RPITCH=100: quat read = one ds_read_b128, bank-perfect for wave64.
//  - (256,3) launch bounds: cap 170 VGPR, need ~105 -> no spill (r8).
//  - Nontemporal full-line output stores.

typedef float f32x4 __attribute__((ext_vector_type(4)));

struct M { float r0,r1,r2,r3,r4,r5,r6,r7,r8,tx,ty,tz; };

__device__ __forceinline__ M loc(float a, float b, float c, float d,
                                 float px, float py, float pz) {
    float inv = rsqrtf(a*a + b*b + c*c + d*d);
    float qw = a*inv, qx = b*inv, qy = c*inv, qz = d*inv;
    float x2 = qx+qx, y2 = qy+qy, z2 = qz+qz;
    float xx = qx*x2, yy = qy*y2, zz = qz*z2;
    float xy = qx*y2, yz = qy*z2, xz = qx*z2;
    float wx = qw*x2, wy = qw*y2, wz = qw*z2;
    M m;
    m.r0 = 1.f-(yy+zz); m.r1 = xy-wz;       m.r2 = xz+wy;
    m.r3 = xy+wz;       m.r4 = 1.f-(xx+zz); m.r5 = yz-wx;
    m.r6 = xz-wy;       m.r7 = yz+wx;       m.r8 = 1.f-(xx+yy);
    m.tx = px; m.ty = py; m.tz = pz;
    return m;
}

__device__ __forceinline__ M mul(const M& a, const M& b) {
    M c;
    c.r0 = a.r0*b.r0 + a.r1*b.r3 + a.r2*b.r6;
    c.r1 = a.r0*b.r1 + a.r1*b.r4 + a.r2*b.r7;
    c.r2 = a.r0*b.r2 + a.r1*b.r5 + a.r2*b.r8;
    c.r3 = a.r3*b.r0 + a.r4*b.r3 + a.r5*b.r6;
    c.r4 = a.r3*b.r1 + a.r4*b.r4 + a.r5*b.r7;
    c.r5 = a.r3*b.r2 + a.r4*b.r5 + a.r5*b.r8;
    c.r6 = a.r6*b.r0 + a.r7*b.r3 + a.r8*b.r6;
    c.r7 = a.r6*b.r1 + a.r7*b.r4 + a.r8*b.r7;
    c.r8 = a.r6*b.r2 + a.r7*b.r5 + a.r8*b.r8;
    c.tx = a.r0*b.tx + a.r1*b.ty + a.r2*b.tz + a.tx;
    c.ty = a.r3*b.tx + a.r4*b.ty + a.r5*b.tz + a.ty;
    c.tz = a.r6*b.tx + a.r7*b.ty + a.r8*b.tz + a.tz;
    return c;
}

#define SPB    64
#define NTHR   256
#define RPITCH 100  // 16B-aligned quat rows -> ds_read_b128, bank-perfect
#define OPITCH 73   // odd pitch overlay (in ldsR region) for outputs
#define PPITCH 73   // odd -> conflict-free b32 pos reads

// Wave-uniform 4-way tree split (verified rounds 7/9/10). MT = matrices
// computed (topological), PR = parent index into MT (-1 = root), writes
// are the suffix from WS. Each of 24 joints written exactly once:
// g0 {0,1,2,4,7,10} g1 {5,8,11,3,6,9} g2 {12,15,13,16,18,20,22}
// g3 {14,17,19,21,23}
constexpr int MT0[6]  = {0,1,2,4,7,10};
constexpr int PR0[6]  = {-1,0,0,1,3,4};
constexpr int MT1[8]  = {0,2,5,8,11,3,6,9};
constexpr int PR1[8]  = {-1,0,1,2,3,0,5,6};
constexpr int MT2[11] = {0,3,6,9,12,15,13,16,18,20,22};
constexpr int PR2[11] = {-1,0,1,2,3,4,3,6,7,8,9};
constexpr int MT3[9]  = {0,3,6,9,14,17,19,21,23};
constexpr int PR3[9]  = {-1,0,1,2,3,4,5,6,7};

// Compute chain; outputs (suffix k>=WS) go to regs ob[3*(k-WS)+e].
template<int NM>
__device__ __forceinline__ void run_chain(const int (&MT)[NM], const int (&PR)[NM],
                                          int WS,
                                          const float* __restrict__ R,
                                          const float* __restrict__ P,
                                          float* __restrict__ ob) {
    M G[NM];
    {
        f32x4 q = *(const f32x4*)(R);
        G[0] = loc(q.x, q.y, q.z, q.w, P[0], P[1], P[2]);
    }
    if (WS == 0) { ob[0]=G[0].tx; ob[1]=G[0].ty; ob[2]=G[0].tz; }
#pragma unroll
    for (int k = 1; k < NM; ++k) {
        const int j = MT[k];
        f32x4 q = *(const f32x4*)(R + 4*j);
        M L = loc(q.x, q.y, q.z, q.w, P[3*j], P[3*j+1], P[3*j+2]);
        G[k] = mul(G[PR[k]], L);
        if (k >= WS) {
            const int o = 3*(k-WS);
            ob[o+0]=G[k].tx; ob[o+1]=G[k].ty; ob[o+2]=G[k].tz;
        }
    }
}

// Scatter held outputs into the out-overlay (pitch 73) of ldsR.
template<int NM>
__device__ __forceinline__ void emit_out(const int (&MT)[NM], int WS,
                                         const float* __restrict__ ob,
                                         float* __restrict__ ovl) {
#pragma unroll
    for (int k = 0; k < NM; ++k) {
        if (k >= WS) {
            const int j = MT[k], o = 3*(k-WS);
            ovl[3*j+0]=ob[o+0]; ovl[3*j+1]=ob[o+1]; ovl[3*j+2]=ob[o+2];
        }
    }
}

__global__ __launch_bounds__(NTHR, 3) void fk_kernel(
    const float* __restrict__ rot,   // B*96 floats (quat wxyz per joint)
    const float* __restrict__ pos,   // B*72 floats
    float*       __restrict__ out,   // B*72 floats
    int B)
{
    __shared__ __align__(16) float ldsR[SPB * RPITCH];  // 25600 B (quats; reused as out)
    __shared__ float ldsP[SPB * PPITCH];                // 18688 B

    const int t = threadIdx.x;
    const size_t baseR = (size_t)blockIdx.x * (SPB*96);   // 6144 dw/block
    const size_t baseP = (size_t)blockIdx.x * (SPB*72);   // 4608 dw/block
    const size_t limR  = (size_t)B * 96;
    const size_t limP  = (size_t)B * 72;

    // ---- phase 0: dense coalesced stage-in ----
    // rot: 6144 dw = 6 full rounds of 256 lanes x4.
    // pos: 4608 dw = 4 full rounds + half round (t<128).
    f32x4 vr[6], vp[5];
#pragma unroll
    for (int i = 0; i < 6; ++i) {
        const size_t gi = baseR + (size_t)(i*1024 + 4*t);
        f32x4 v = {0.f,0.f,0.f,0.f};
        if (gi < limR) v = *(const f32x4*)(rot + gi);
        vr[i] = v;
    }
#pragma unroll
    for (int i = 0; i < 5; ++i) {
        const bool g = (i < 4) || (t < 128);
        const size_t gi = baseP + (size_t)(i*1024 + 4*t);
        f32x4 v = {0.f,0.f,0.f,0.f};
        if (g && gi < limP) v = *(const f32x4*)(pos + gi);
        vp[i] = v;
    }
    // scatter to pitched LDS (x4 chunks never straddle a sample: 96%4==72%4==0)
#pragma unroll
    for (int i = 0; i < 6; ++i) {
        const int f = i*1024 + 4*t;
        const int s = f / 96, r = f - 96*s;
        *(f32x4*)(ldsR + s*RPITCH + r) = vr[i];   // aligned b128 write
    }
#pragma unroll
    for (int i = 0; i < 5; ++i) {
        if ((i < 4) || (t < 128)) {
            const int f = i*1024 + 4*t;
            const int s = f / 72, r = f - 72*s;
            float* d = ldsP + s*PPITCH + r;
            d[0]=vp[i].x; d[1]=vp[i].y; d[2]=vp[i].z; d[3]=vp[i].w;
        }
    }
    __syncthreads();

    // ---- phase 1: compute. wave w = subtree group, lane l = sample ----
    const int w = t >> 6, l = t & 63;
    const int b = blockIdx.x * SPB + l;
    const bool act = (b < B);
    const float* R = ldsR + l * RPITCH;
    const float* P = ldsP + l * PPITCH;

    float ob[21];   // held outputs (max 7 joints x 3, group g2)
    if (act) {
        switch (w) {
            case 0:  run_chain(MT0, PR0, 0, R, P, ob); break;
            case 1:  run_chain(MT1, PR1, 2, R, P, ob); break;
            case 2:  run_chain(MT2, PR2, 4, R, P, ob); break;
            default: run_chain(MT3, PR3, 4, R, P, ob); break;
        }
    }
    __syncthreads();   // all quat reads done -> ldsR region is dead

    // ---- phase 2: scatter outputs into ldsR overlay at pitch 73 ----
    if (act) {
        float* ovl = ldsR + l * OPITCH;    // 64*73=4672 dw < 6400 dw region
        switch (w) {
            case 0:  emit_out(MT0, 0, ob, ovl); break;
            case 1:  emit_out(MT1, 2, ob, ovl); break;
            case 2:  emit_out(MT2, 4, ob, ovl); break;
            default: emit_out(MT3, 4, ob, ovl); break;
        }
    }
    __syncthreads();

    // ---- phase 3: dense coalesced nontemporal dwordx4 store ----
#pragma unroll
    for (int n = 0; n < 5; ++n) {
        if ((n < 4) || (t < 128)) {
            const int F = n*1024 + 4*t;
            const int s = F / 72, r = F - 72*s;
            const size_t gi = baseP + (size_t)F;
            if (gi < limP) {
                f32x4 v = { ldsR[s*OPITCH+r+0], ldsR[s*OPITCH+r+1],
                            ldsR[s*OPITCH+r+2], ldsR[s*OPITCH+r+3] };
                __builtin_nontemporal_store(v, (f32x4*)(out + gi));
            }
        }
    }
}

extern "C" void kernel_launch(void* const* d_in, const int* in_sizes, int n_in,
                              void* d_out, int out_size, void* d_ws, size_t ws_size,
                              hipStream_t stream) {
    const int B = out_size / 72;           // (B,24,3)
    const void* rot = nullptr;
    const void* pos = nullptr;
    for (int i = 0; i < n_in; ++i) {       // resolve by size, not order
        if      (in_sizes[i] == B * 96) rot = d_in[i];
        else if (in_sizes[i] == B * 72) pos = d_in[i];
    }
    if (!rot) rot = d_in[2];
    if (!pos) pos = d_in[1];

    const int grid = (B + SPB - 1) / SPB;  // 2048 blocks @ B=131072
    fk_kernel<<<grid, NTHR, 0, stream>>>(
        (const float*)rot, (const float*)pos, (float*)d_out, B);
}

// Round 7
// 123.954 us; speedup vs baseline: 1.1474x; 1.0965x over previous
//
#include <hip/hip_runtime.h>

// ForwardKinematics fp32: rotations (B,24,4) wxyz + positions (B,24,3)
// -> global joint positions (B,24,3). Fixed SMPL tree.
//
// Round 12 (resubmit; round-6 bench was an infra failure, not a result).
// Producer/consumer wave specialization:
//  - r11 diagnosis: VALU 40% / HBM 27% / occ 24% -- no pipe >41%, the
//    block-wide phases ALTERNATE pipes. Fix: role-split waves so HBM
//    demand is continuous per CU.
//  - 512 thr = 4 compute waves + 4 memory waves. Persistent grid 256
//    (1 block/CU), 8 chunks of SPB=64 per block, double-buffered LDS.
//  - Per generation (ONE barrier): compute waves: chains on buf q ->
//    ldsO[q]. Mem waves: issue loads chunk c+1; store chunk c-1 from
//    ldsO[q^1] (load latency hides under store); scatter into buf q^1.
//  - LDS 123 KB static (2x R/P/O) -> 1 block/CU, 8 waves.
//  - (512,2): 256-VGPR cap, live ~90 -> no spill (r8 lesson).
//  - 4-way wave-uniform DAG split unchanged (verified r7..r11).

typedef float f32x4 __attribute__((ext_vector_type(4)));

struct M { float r0,r1,r2,r3,r4,r5,r6,r7,r8,tx,ty,tz; };

__device__ __forceinline__ M loc(float a, float b, float c, float d,
                                 float px, float py, float pz) {
    float inv = rsqrtf(a*a + b*b + c*c + d*d);
    float qw = a*inv, qx = b*inv, qy = c*inv, qz = d*inv;
    float x2 = qx+qx, y2 = qy+qy, z2 = qz+qz;
    float xx = qx*x2, yy = qy*y2, zz = qz*z2;
    float xy = qx*y2, yz = qy*z2, xz = qx*z2;
    float wx = qw*x2, wy = qw*y2, wz = qw*z2;
    M m;
    m.r0 = 1.f-(yy+zz); m.r1 = xy-wz;       m.r2 = xz+wy;
    m.r3 = xy+wz;       m.r4 = 1.f-(xx+zz); m.r5 = yz-wx;
    m.r6 = xz-wy;       m.r7 = yz+wx;       m.r8 = 1.f-(xx+yy);
    m.tx = px; m.ty = py; m.tz = pz;
    return m;
}

__device__ __forceinline__ M mul(const M& a, const M& b) {
    M c;
    c.r0 = a.r0*b.r0 + a.r1*b.r3 + a.r2*b.r6;
    c.r1 = a.r0*b.r1 + a.r1*b.r4 + a.r2*b.r7;
    c.r2 = a.r0*b.r2 + a.r1*b.r5 + a.r2*b.r8;
    c.r3 = a.r3*b.r0 + a.r4*b.r3 + a.r5*b.r6;
    c.r4 = a.r3*b.r1 + a.r4*b.r4 + a.r5*b.r7;
    c.r5 = a.r3*b.r2 + a.r4*b.r5 + a.r5*b.r8;
    c.r6 = a.r6*b.r0 + a.r7*b.r3 + a.r8*b.r6;
    c.r7 = a.r6*b.r1 + a.r7*b.r4 + a.r8*b.r7;
    c.r8 = a.r6*b.r2 + a.r7*b.r5 + a.r8*b.r8;
    c.tx = a.r0*b.tx + a.r1*b.ty + a.r2*b.tz + a.tx;
    c.ty = a.r3*b.tx + a.r4*b.ty + a.r5*b.tz + a.ty;
    c.tz = a.r6*b.tx + a.r7*b.ty + a.r8*b.tz + a.tz;
    return c;
}

#define SPB    64
#define NTHR   512
#define GRIDP  256   // persistent blocks: 1 per CU
#define RPITCH 100   // 16B-aligned quat rows -> ds_read_b128
#define PPITCH 73    // odd -> conflict-free b32 access

// Wave-uniform 4-way tree split (verified rounds 7-11). MT = matrices
// computed (topological), PR = parent index into MT (-1 = root), writes
// are the suffix from WS. Each of 24 joints written exactly once.
constexpr int MT0[6]  = {0,1,2,4,7,10};
constexpr int PR0[6]  = {-1,0,0,1,3,4};
constexpr int MT1[8]  = {0,2,5,8,11,3,6,9};
constexpr int PR1[8]  = {-1,0,1,2,3,0,5,6};
constexpr int MT2[11] = {0,3,6,9,12,15,13,16,18,20,22};
constexpr int PR2[11] = {-1,0,1,2,3,4,3,6,7,8,9};
constexpr int MT3[9]  = {0,3,6,9,14,17,19,21,23};
constexpr int PR3[9]  = {-1,0,1,2,3,4,5,6,7};

template<int NM>
__device__ __forceinline__ void run_chain(const int (&MT)[NM], const int (&PR)[NM],
                                          int WS,
                                          const float* __restrict__ R,
                                          const float* __restrict__ P,
                                          float* __restrict__ O) {
    M G[NM];
    {
        f32x4 q = *(const f32x4*)(R);
        G[0] = loc(q.x, q.y, q.z, q.w, P[0], P[1], P[2]);
    }
    if (WS == 0) { O[0]=G[0].tx; O[1]=G[0].ty; O[2]=G[0].tz; }
#pragma unroll
    for (int k = 1; k < NM; ++k) {
        const int j = MT[k];
        f32x4 q = *(const f32x4*)(R + 4*j);
        M L = loc(q.x, q.y, q.z, q.w, P[3*j], P[3*j+1], P[3*j+2]);
        G[k] = mul(G[PR[k]], L);
        if (k >= WS) { O[3*j]=G[k].tx; O[3*j+1]=G[k].ty; O[3*j+2]=G[k].tz; }
    }
}

// ---- memory-wave helpers (mt in [0,256)) ----
__device__ __forceinline__ void load_regs(int c, int mt,
                                          const float* __restrict__ rot,
                                          const float* __restrict__ pos,
                                          size_t limR, size_t limP,
                                          f32x4 (&vr)[6], f32x4 (&vp)[5]) {
    const size_t baseR = (size_t)c * (SPB*96);   // 6144 dw/chunk
    const size_t baseP = (size_t)c * (SPB*72);   // 4608 dw/chunk
#pragma unroll
    for (int i = 0; i < 6; ++i) {
        const size_t gi = baseR + (size_t)(i*1024 + 4*mt);
        f32x4 v = {0.f,0.f,0.f,0.f};
        if (gi < limR) v = *(const f32x4*)(rot + gi);
        vr[i] = v;
    }
#pragma unroll
    for (int i = 0; i < 5; ++i) {
        const bool g = (i < 4) || (mt < 128);
        const size_t gi = baseP + (size_t)(i*1024 + 4*mt);
        f32x4 v = {0.f,0.f,0.f,0.f};
        if (g && gi < limP) v = *(const f32x4*)(pos + gi);
        vp[i] = v;
    }
}

__device__ __forceinline__ void scatter_lds(int mt,
                                            float* __restrict__ Rb,
                                            float* __restrict__ Pb,
                                            const f32x4 (&vr)[6],
                                            const f32x4 (&vp)[5]) {
#pragma unroll
    for (int i = 0; i < 6; ++i) {
        const int f = i*1024 + 4*mt;
        const int s = f / 96, r = f - 96*s;
        *(f32x4*)(Rb + s*RPITCH + r) = vr[i];     // aligned b128 write
    }
#pragma unroll
    for (int i = 0; i < 5; ++i) {
        if ((i < 4) || (mt < 128)) {
            const int f = i*1024 + 4*mt;
            const int s = f / 72, r = f - 72*s;
            float* d = Pb + s*PPITCH + r;
            d[0]=vp[i].x; d[1]=vp[i].y; d[2]=vp[i].z; d[3]=vp[i].w;
        }
    }
}

__device__ __forceinline__ void store_chunk(const float* __restrict__ Ob,
                                            int c, int mt, size_t limP,
                                            float* __restrict__ out) {
    const size_t baseO = (size_t)c * (SPB*72);
#pragma unroll
    for (int n = 0; n < 5; ++n) {
        if ((n < 4) || (mt < 128)) {
            const int F = n*1024 + 4*mt;
            const int s = F / 72, r = F - 72*s;
            const size_t gi = baseO + (size_t)F;
            if (gi < limP) {
                f32x4 v = { Ob[s*PPITCH+r+0], Ob[s*PPITCH+r+1],
                            Ob[s*PPITCH+r+2], Ob[s*PPITCH+r+3] };
                __builtin_nontemporal_store(v, (f32x4*)(out + gi));
            }
        }
    }
}

__global__ __launch_bounds__(NTHR, 2) void fk_kernel(
    const float* __restrict__ rot,   // B*96 floats (quat wxyz per joint)
    const float* __restrict__ pos,   // B*72 floats
    float*       __restrict__ out,   // B*72 floats
    int B)
{
    __shared__ __align__(16) float ldsR[2][SPB * RPITCH];  // 2 x 25600 B
    __shared__ float ldsP[2][SPB * PPITCH];                // 2 x 18688 B
    __shared__ float ldsO[2][SPB * PPITCH];                // 2 x 18688 B
                                                           // total 125952 B

    const int t   = threadIdx.x;
    const int w   = t >> 6;
    const bool cw = (w < 4);          // compute waves 0..3, mem waves 4..7
    const int mt  = t & 255;
    const int nch = (B + SPB - 1) / SPB;
    const size_t limR = (size_t)B * 96;
    const size_t limP = (size_t)B * 72;

    // ---- prologue: mem waves stage chunk c0 into buffer 0 ----
    const int c0 = blockIdx.x;
    if (!cw && c0 < nch) {
        f32x4 vr[6], vp[5];
        load_regs(c0, mt, rot, pos, limR, limP, vr, vp);
        scatter_lds(mt, ldsR[0], ldsP[0], vr, vp);
    }
    __syncthreads();

    int i = 0, c = c0;
    for (; c < nch; c += GRIDP, ++i) {
        const int q = i & 1;
        if (cw) {
            // ---- compute chunk c from buffer q -> ldsO[q] ----
            const int l = t & 63;
            const int b = c * SPB + l;
            if (b < B) {
                const float* R = &ldsR[q][l * RPITCH];
                const float* P = &ldsP[q][l * PPITCH];
                float*       O = &ldsO[q][l * PPITCH];
                switch (w) {
                    case 0:  run_chain(MT0, PR0, 0, R, P, O); break;
                    case 1:  run_chain(MT1, PR1, 2, R, P, O); break;
                    case 2:  run_chain(MT2, PR2, 4, R, P, O); break;
                    default: run_chain(MT3, PR3, 4, R, P, O); break;
                }
            }
        } else {
            // ---- 1) issue next chunk's 11 global loads ----
            const int cn = c + GRIDP;
            const bool ldv = (cn < nch);
            f32x4 vr[6], vp[5];
            if (ldv) load_regs(cn, mt, rot, pos, limR, limP, vr, vp);
            // ---- 2) store chunk c-GRIDP from ldsO[q^1] (hides load lat) ----
            if (i > 0) store_chunk(ldsO[q^1], c - GRIDP, mt, limP, out);
            // ---- 3) scatter loads into buffers q^1 ----
            if (ldv) scatter_lds(mt, ldsR[q^1], ldsP[q^1], vr, vp);
        }
        __syncthreads();
    }

    // ---- epilogue: store the final chunk's output ----
    if (!cw && i > 0)
        store_chunk(ldsO[(i-1) & 1], c - GRIDP, mt, limP, out);
}

extern "C" void kernel_launch(void* const* d_in, const int* in_sizes, int n_in,
                              void* d_out, int out_size, void* d_ws, size_t ws_size,
                              hipStream_t stream) {
    const int B = out_size / 72;           // (B,24,3)
    const void* rot = nullptr;
    const void* pos = nullptr;
    for (int i = 0; i < n_in; ++i) {       // resolve by size, not order
        if      (in_sizes[i] == B * 96) rot = d_in[i];
        else if (in_sizes[i] == B * 72) pos = d_in[i];
    }
    if (!rot) rot = d_in[2];
    if (!pos) pos = d_in[1];

    const int nch  = (B + SPB - 1) / SPB;  // 2048 chunks @ B=131072
    const int grid = (nch < GRIDP) ? nch : GRIDP;
    fk_kernel<<<grid, NTHR, 0, stream>>>(
        (const float*)rot, (const float*)pos, (float*)d_out, B);
}